// Round 5
// baseline (188.447 us; speedup 1.0000x reference)
//
#include <hip/hip_runtime.h>
#include <hip/hip_bf16.h>
#include <stdint.h>

#define B 16
#define N 32
#define C 512
#define FEAT 224

typedef float nfloat4 __attribute__((ext_vector_type(4)));  // native vec for nontemporal builtins

// ---------------- Kernel A: conf map -> sigmoid -> avgpool8 ----------------
// grid = B * 4 (4 chunks of 196 cells), block = 256. Block 0 also zeros the
// per-batch arrival counters used by logits_kernel (prior dispatch => visible).
__global__ __launch_bounds__(256) void att_kernel(const float* __restrict__ confs,
                                                  const float* __restrict__ boxes,
                                                  float* __restrict__ att /* [B][784] */,
                                                  uint32_t* __restrict__ cnt /* [B] */) {
    int b = blockIdx.x >> 2;
    int chunk = blockIdx.x & 3;
    int t = threadIdx.x;

    if (blockIdx.x == 0 && t < B) cnt[t] = 0u;

    __shared__ int4 ib[N];
    __shared__ float sconf[N];
    __shared__ uint32_t rm[FEAT], cm[FEAT];

    if (t < N) {
        const float* bb = boxes + (size_t)(b * N + t) * 4;
        int x1 = (int)floorf(bb[0] * 224.f);
        int y1 = (int)floorf(bb[1] * 224.f);
        int x2 = (int)floorf(bb[2] * 224.f);
        int y2 = (int)floorf(bb[3] * 224.f);
        ib[t] = make_int4(x1, y1, x2, y2);
        sconf[t] = confs[b * N + t];
    }
    __syncthreads();

    if (t < FEAT) {
        uint32_t r = 0, c = 0;
        for (int n = 0; n < N; ++n) {
            int4 v = ib[n];
            if (t >= v.y && t < v.w) r |= (1u << n);
            if (t >= v.x && t < v.z) c |= (1u << n);
        }
        rm[t] = r;
        cm[t] = c;
    }
    __syncthreads();

    if (t < 196) {
        int cell = chunk * 196 + t;      // 0..783
        int cy = cell / 28, cx = cell % 28;
        float sum = 0.f;
        for (int dy = 0; dy < 8; ++dy) {
            uint32_t r = rm[cy * 8 + dy];
            for (int dx = 0; dx < 8; ++dx) {
                uint32_t m = r & cm[cx * 8 + dx];
                float v = 0.f;
                while (m) {
                    int n = __ffs(m) - 1;
                    v += sconf[n];
                    m &= m - 1;
                }
                sum += 1.f / (1.f + __expf(-v));   // sigmoid
            }
        }
        att[b * 784 + cell] = sum * (1.f / 64.f);
    }
}

// ---------------- Kernel B: logits + last-block softmax -> w --------------
// grid = B * C/4 = 2048 blocks, block = 256 (4 waves), one wave per channel.
// 128 blocks per batch; the last to finish computes softmax for all 3 levels.
__global__ __launch_bounds__(256) void logits_kernel(const float* __restrict__ f0,
                                                     const float* __restrict__ f1,
                                                     const float* __restrict__ f2,
                                                     const float* __restrict__ att,
                                                     float* __restrict__ logits /* [3][B][C] */,
                                                     float* __restrict__ w /* [3][B][C] */,
                                                     uint32_t* __restrict__ cnt /* [B] */) {
    int b = blockIdx.x >> 7;          // / 128
    int cg = blockIdx.x & 127;        // channel group of 4
    int t = threadIdx.x;

    __shared__ __align__(16) float a8[784];
    __shared__ __align__(16) float a16[196];
    __shared__ float a32[49];

    {
        const float4* abv = (const float4*)(att + b * 784);
        float4* a8v = (float4*)a8;
        if (t < 196) a8v[t] = abv[t];
    }
    __syncthreads();
    if (t < 196) {
        int i = t / 14, j = t % 14;
        a16[t] = 0.25f * (a8[(2 * i) * 28 + 2 * j] + a8[(2 * i) * 28 + 2 * j + 1] +
                          a8[(2 * i + 1) * 28 + 2 * j] + a8[(2 * i + 1) * 28 + 2 * j + 1]);
    }
    __syncthreads();
    if (t < 49) {
        int i = t / 7, j = t % 7;
        a32[t] = 0.25f * (a16[(2 * i) * 14 + 2 * j] + a16[(2 * i) * 14 + 2 * j + 1] +
                          a16[(2 * i + 1) * 14 + 2 * j] + a16[(2 * i + 1) * 14 + 2 * j + 1]);
    }
    __syncthreads();

    int wave = t >> 6, lane = t & 63;
    int c = cg * 4 + wave;

    const float4* p0 = (const float4*)(f0 + (size_t)(b * C + c) * 784); // 196 float4
    const float4* p1 = (const float4*)(f1 + (size_t)(b * C + c) * 196); // 49 float4
    const float*  p2 = f2 + (size_t)(b * C + c) * 49;                   // 49 floats
    const float4* a8v = (const float4*)a8;
    const float4* a16v = (const float4*)a16;

    float4 x0 = p0[lane];
    float4 x1 = p0[lane + 64];
    float4 x2 = p0[lane + 128];
    float4 x3 = (lane < 4) ? p0[lane + 192] : make_float4(0.f, 0.f, 0.f, 0.f);
    float4 y0 = (lane < 49) ? p1[lane] : make_float4(0.f, 0.f, 0.f, 0.f);
    float  z0 = (lane < 49) ? p2[lane] : 0.f;

    float4 b0 = a8v[lane];
    float4 b1 = a8v[lane + 64];
    float4 b2 = a8v[lane + 128];
    float4 b3 = (lane < 4) ? a8v[lane + 192] : make_float4(0.f, 0.f, 0.f, 0.f);

    float s0 = x0.x * b0.x + x0.y * b0.y + x0.z * b0.z + x0.w * b0.w;
    s0 += x1.x * b1.x + x1.y * b1.y + x1.z * b1.z + x1.w * b1.w;
    s0 += x2.x * b2.x + x2.y * b2.y + x2.z * b2.z + x2.w * b2.w;
    s0 += x3.x * b3.x + x3.y * b3.y + x3.z * b3.z + x3.w * b3.w;

    float s1 = 0.f, s2 = 0.f;
    if (lane < 49) {
        float4 c1 = a16v[lane];
        s1 = y0.x * c1.x + y0.y * c1.y + y0.z * c1.z + y0.w * c1.w;
        s2 = z0 * a32[lane];
    }

    for (int o = 32; o; o >>= 1) {
        s0 += __shfl_down(s0, o);
        s1 += __shfl_down(s1, o);
        s2 += __shfl_down(s2, o);
    }
    if (lane == 0) {
        int idx = b * C + c;
        __hip_atomic_store(&logits[idx], s0, __ATOMIC_RELAXED, __HIP_MEMORY_SCOPE_AGENT);
        __hip_atomic_store(&logits[B * C + idx], s1, __ATOMIC_RELAXED, __HIP_MEMORY_SCOPE_AGENT);
        __hip_atomic_store(&logits[2 * B * C + idx], s2, __ATOMIC_RELAXED, __HIP_MEMORY_SCOPE_AGENT);
    }

    // ---- last-block-per-batch computes softmax for (level 0..2, b) ----
    __shared__ int lastFlag;
    __syncthreads();                       // drains the stores above
    if (t == 0) {
        __threadfence();
        lastFlag = (atomicAdd(&cnt[b], 1u) == 127u);
    }
    __syncthreads();
    if (lastFlag && wave < 3) {
        const float* lp = logits + (wave * B + b) * C;
        float v[8];
        float mx = -1e30f;
        #pragma unroll
        for (int k = 0; k < 8; ++k) {
            v[k] = __hip_atomic_load(&lp[lane + 64 * k], __ATOMIC_RELAXED,
                                     __HIP_MEMORY_SCOPE_AGENT);
            mx = fmaxf(mx, v[k]);
        }
        for (int o = 32; o; o >>= 1) mx = fmaxf(mx, __shfl_xor(mx, o));
        float s = 0.f;
        #pragma unroll
        for (int k = 0; k < 8; ++k) {
            v[k] = __expf(v[k] - mx);
            s += v[k];
        }
        for (int o = 32; o; o >>= 1) s += __shfl_xor(s, o);
        float inv = 1.f / s;
        float* wp = w + (wave * B + b) * C;
        #pragma unroll
        for (int k = 0; k < 8; ++k) wp[lane + 64 * k] = v[k] * inv;
    }
}

// ------------- Kernel C: out = feat * w (w read direct from L2) -----------
// grid = 1152: L0 = 16b x 56 slices (1792 f4), L1 = 16 x 14 (1792), L2 = 16 x 2 (3136)
#define SLAB4 131712                 // 526848/4 per-batch out float4s

__global__ __launch_bounds__(256) void scale_kernel(const float4* __restrict__ f0,
                                                    const float4* __restrict__ f1,
                                                    const float4* __restrict__ f2,
                                                    const float* __restrict__ w /* [3][B][C] */,
                                                    nfloat4* __restrict__ out) {
    int bid = blockIdx.x;
    int t = threadIdx.x;
    int level, b, sl;
    if (bid < 896)       { level = 0; b = bid / 56;          sl = bid % 56; }
    else if (bid < 1120) { level = 1; b = (bid - 896) / 14;  sl = (bid - 896) % 14; }
    else                 { level = 2; b = (bid - 1120) >> 1; sl = (bid - 1120) & 1; }

    if (level == 0) {
        int r4 = sl * 1792 + t;                       // [0, 100352)
        const float4* src = f0 + (size_t)b * 100352;
        const float* wr = w + b * C;
        nfloat4* dst = out + (size_t)b * SLAB4;
        #pragma unroll
        for (int k = 0; k < 7; ++k, r4 += 256) {
            float4 x = src[r4];
            float wv = wr[(uint32_t)r4 / 196u];       // 196 f4 per channel
            nfloat4 y = {x.x * wv, x.y * wv, x.z * wv, x.w * wv};
            __builtin_nontemporal_store(y, &dst[r4]);
        }
    } else if (level == 1) {
        int r4 = sl * 1792 + t;                       // [0, 25088)
        const float4* src = f1 + (size_t)b * 25088;
        const float* wr = w + (B + b) * C;
        nfloat4* dst = out + (size_t)b * SLAB4 + 100352;
        #pragma unroll
        for (int k = 0; k < 7; ++k, r4 += 256) {
            float4 x = src[r4];
            float wv = wr[(uint32_t)r4 / 49u];        // 49 f4 per channel
            nfloat4 y = {x.x * wv, x.y * wv, x.z * wv, x.w * wv};
            __builtin_nontemporal_store(y, &dst[r4]);
        }
    } else {
        int r4 = sl * 3136 + t;                       // [0, 6272)
        int end = sl * 3136 + 3136;
        const float4* src = f2 + (size_t)b * 6272;
        const float* wr = w + (2 * B + b) * C;
        nfloat4* dst = out + (size_t)b * SLAB4 + 125440;
        #pragma unroll
        for (int k = 0; k < 13; ++k, r4 += 256) {
            if (r4 < end) {
                float4 x = src[r4];
                uint32_t e = (uint32_t)r4 * 4u;       // element idx, 49 floats/channel
                nfloat4 y = {x.x * wr[e / 49u], x.y * wr[(e + 1u) / 49u],
                             x.z * wr[(e + 2u) / 49u], x.w * wr[(e + 3u) / 49u]};
                __builtin_nontemporal_store(y, &dst[r4]);
            }
        }
    }
}

// --------------------------------------------------------------------------
extern "C" void kernel_launch(void* const* d_in, const int* in_sizes, int n_in,
                              void* d_out, int out_size, void* d_ws, size_t ws_size,
                              hipStream_t stream) {
    const float* confs = (const float*)d_in[0];   // [16][32]
    const float* boxes = (const float*)d_in[1];   // [16][32][4]
    const float* f0 = (const float*)d_in[2];      // [16][512][28][28]
    const float* f1 = (const float*)d_in[3];      // [16][512][14][14]
    const float* f2 = (const float*)d_in[4];      // [16][512][7][7]
    float* out = (float*)d_out;

    float* ws = (float*)d_ws;
    float* att = ws;                                  // 16*784   = 12544 floats
    float* logits = ws + 12544;                       // 3*16*512 = 24576 floats
    float* w = ws + 12544 + 24576;                    // 3*16*512 = 24576 floats
    uint32_t* cnt = (uint32_t*)(ws + 12544 + 2 * 24576);  // 16 uints

    att_kernel<<<B * 4, 256, 0, stream>>>(confs, boxes, att, cnt);
    logits_kernel<<<B * C / 4, 256, 0, stream>>>(f0, f1, f2, att, logits, w, cnt);
    scale_kernel<<<1152, 256, 0, stream>>>((const float4*)f0, (const float4*)f1,
                                           (const float4*)f2, w, (nfloat4*)out);
}

// Round 6
// 165.033 us; speedup vs baseline: 1.1419x; 1.1419x over previous
//
#include <hip/hip_runtime.h>
#include <hip/hip_bf16.h>
#include <stdint.h>

#define B 16
#define N 32
#define C 512
#define FEAT 224
#define ATT_STRIDE 1040   // 784 + 196 + 49 = 1029, padded to 16B multiple

// ------- Kernel A: conf map -> sigmoid -> avgpool8/16/32 pyramid ----------
// grid = B (one block per batch), block = 256.
// Writes att[b*1040 + 0..783] = 28x28, [784..979] = 14x14, [980..1028] = 7x7.
__global__ __launch_bounds__(256) void att_kernel(const float* __restrict__ confs,
                                                  const float* __restrict__ boxes,
                                                  float* __restrict__ att) {
    int b = blockIdx.x;
    int t = threadIdx.x;

    __shared__ int4 ib[N];
    __shared__ float sconf[N];
    __shared__ uint32_t rm[FEAT], cm[FEAT];
    __shared__ float sa8[784];
    __shared__ float sa16[196];

    if (t < N) {
        const float* bb = boxes + (size_t)(b * N + t) * 4;
        int x1 = (int)floorf(bb[0] * 224.f);
        int y1 = (int)floorf(bb[1] * 224.f);
        int x2 = (int)floorf(bb[2] * 224.f);
        int y2 = (int)floorf(bb[3] * 224.f);
        ib[t] = make_int4(x1, y1, x2, y2);
        sconf[t] = confs[b * N + t];
    }
    __syncthreads();

    if (t < FEAT) {
        uint32_t r = 0, c = 0;
        for (int n = 0; n < N; ++n) {
            int4 v = ib[n];
            if (t >= v.y && t < v.w) r |= (1u << n);
            if (t >= v.x && t < v.z) c |= (1u << n);
        }
        rm[t] = r;
        cm[t] = c;
    }
    __syncthreads();

    float* ab = att + (size_t)b * ATT_STRIDE;
    for (int cell = t; cell < 784; cell += 256) {
        int cy = cell / 28, cx = cell % 28;
        float sum = 0.f;
        for (int dy = 0; dy < 8; ++dy) {
            uint32_t r = rm[cy * 8 + dy];
            for (int dx = 0; dx < 8; ++dx) {
                uint32_t m = r & cm[cx * 8 + dx];
                float v = 0.f;
                while (m) {
                    int n = __ffs(m) - 1;
                    v += sconf[n];
                    m &= m - 1;
                }
                sum += 1.f / (1.f + __expf(-v));   // sigmoid
            }
        }
        float val = sum * (1.f / 64.f);
        sa8[cell] = val;
        ab[cell] = val;
    }
    __syncthreads();

    if (t < 196) {
        int i = t / 14, j = t % 14;
        float v = 0.25f * (sa8[(2 * i) * 28 + 2 * j] + sa8[(2 * i) * 28 + 2 * j + 1] +
                           sa8[(2 * i + 1) * 28 + 2 * j] + sa8[(2 * i + 1) * 28 + 2 * j + 1]);
        sa16[t] = v;
        ab[784 + t] = v;
    }
    __syncthreads();

    if (t < 49) {
        int i = t / 7, j = t % 7;
        float v = 0.25f * (sa16[(2 * i) * 14 + 2 * j] + sa16[(2 * i) * 14 + 2 * j + 1] +
                           sa16[(2 * i + 1) * 14 + 2 * j] + sa16[(2 * i + 1) * 14 + 2 * j + 1]);
        ab[980 + t] = v;
    }
}

// ---------------- Kernel B: logits[l][b][c] = sum_hw feat*att -------------
// grid = B * C/4 = 2048 blocks, block = 256 (4 waves), one wave per channel.
__global__ __launch_bounds__(256) void logits_kernel(const float* __restrict__ f0,
                                                     const float* __restrict__ f1,
                                                     const float* __restrict__ f2,
                                                     const float* __restrict__ att,
                                                     float* __restrict__ logits /* [3][B][C] */) {
    int b = blockIdx.x >> 7;          // / 128
    int cg = blockIdx.x & 127;        // channel group of 4
    int t = threadIdx.x;

    __shared__ __align__(16) float sa[ATT_STRIDE];   // [a8 784 | a16 196 | a32 49 | pad]

    {
        const float4* abv = (const float4*)(att + (size_t)b * ATT_STRIDE);
        float4* sv = (float4*)sa;
        for (int i = t; i < ATT_STRIDE / 4; i += 256) sv[i] = abv[i];
    }
    __syncthreads();

    int wave = t >> 6, lane = t & 63;
    int c = cg * 4 + wave;

    const float4* p0 = (const float4*)(f0 + (size_t)(b * C + c) * 784); // 196 float4
    const float4* p1 = (const float4*)(f1 + (size_t)(b * C + c) * 196); // 49 float4
    const float*  p2 = f2 + (size_t)(b * C + c) * 49;                   // 49 floats
    const float4* a8v  = (const float4*)sa;
    const float4* a16v = (const float4*)(sa + 784);
    const float*  a32p = sa + 980;

    float4 x0 = p0[lane];
    float4 x1 = p0[lane + 64];
    float4 x2 = p0[lane + 128];
    float4 x3 = (lane < 4) ? p0[lane + 192] : make_float4(0.f, 0.f, 0.f, 0.f);
    float4 y0 = (lane < 49) ? p1[lane] : make_float4(0.f, 0.f, 0.f, 0.f);
    float  z0 = (lane < 49) ? p2[lane] : 0.f;

    float4 b0 = a8v[lane];
    float4 b1 = a8v[lane + 64];
    float4 b2 = a8v[lane + 128];
    float4 b3 = (lane < 4) ? a8v[lane + 192] : make_float4(0.f, 0.f, 0.f, 0.f);

    float s0 = x0.x * b0.x + x0.y * b0.y + x0.z * b0.z + x0.w * b0.w;
    s0 += x1.x * b1.x + x1.y * b1.y + x1.z * b1.z + x1.w * b1.w;
    s0 += x2.x * b2.x + x2.y * b2.y + x2.z * b2.z + x2.w * b2.w;
    s0 += x3.x * b3.x + x3.y * b3.y + x3.z * b3.z + x3.w * b3.w;

    float s1 = 0.f, s2 = 0.f;
    if (lane < 49) {
        float4 c1 = a16v[lane];
        s1 = y0.x * c1.x + y0.y * c1.y + y0.z * c1.z + y0.w * c1.w;
        s2 = z0 * a32p[lane];
    }

    for (int o = 32; o; o >>= 1) {
        s0 += __shfl_down(s0, o);
        s1 += __shfl_down(s1, o);
        s2 += __shfl_down(s2, o);
    }
    if (lane == 0) {
        int idx = b * C + c;
        logits[idx] = s0;
        logits[B * C + idx] = s1;
        logits[2 * B * C + idx] = s2;
    }
}

// ------- Kernel C: softmax(logits row) in-block, then out = feat * w -------
// grid = 1152: L0 = 16b x 56 slices (1792 f4), L1 = 16 x 14 (1792), L2 = 16 x 2 (3136)
#define SLAB4 131712                 // 526848/4 per-batch out float4s

__global__ __launch_bounds__(256) void scale_kernel(const float4* __restrict__ f0,
                                                    const float4* __restrict__ f1,
                                                    const float4* __restrict__ f2,
                                                    const float* __restrict__ logits /* [3][B][C] */,
                                                    float4* __restrict__ out) {
    int bid = blockIdx.x;
    int t = threadIdx.x;
    int level, b, sl;
    if (bid < 896)       { level = 0; b = bid / 56;          sl = bid % 56; }
    else if (bid < 1120) { level = 1; b = (bid - 896) / 14;  sl = (bid - 896) % 14; }
    else                 { level = 2; b = (bid - 1120) >> 1; sl = (bid - 1120) & 1; }

    // ---- block softmax over C for (level, b) ----
    __shared__ float wsm[C];
    __shared__ float red[8];
    int wave = t >> 6, lane = t & 63;
    const float* lp = logits + (level * B + b) * C;
    float v0 = lp[t], v1 = lp[t + 256];
    float mx = fmaxf(v0, v1);
    for (int o = 32; o; o >>= 1) mx = fmaxf(mx, __shfl_xor(mx, o));
    if (lane == 0) red[wave] = mx;
    __syncthreads();
    mx = fmaxf(fmaxf(red[0], red[1]), fmaxf(red[2], red[3]));
    float e0 = __expf(v0 - mx), e1 = __expf(v1 - mx);
    float s = e0 + e1;
    for (int o = 32; o; o >>= 1) s += __shfl_xor(s, o);
    if (lane == 0) red[4 + wave] = s;
    __syncthreads();
    float inv = 1.f / (red[4] + red[5] + red[6] + red[7]);
    wsm[t] = e0 * inv;
    wsm[t + 256] = e1 * inv;
    __syncthreads();

    // ---- stream the slice ----
    if (level == 0) {
        int r4 = sl * 1792 + t;                       // [0, 100352)
        const float4* src = f0 + (size_t)b * 100352;
        float4* dst = out + (size_t)b * SLAB4;
        #pragma unroll
        for (int k = 0; k < 7; ++k, r4 += 256) {
            float4 x = src[r4];
            float wv = wsm[(uint32_t)r4 / 196u];      // 196 f4 per channel
            dst[r4] = make_float4(x.x * wv, x.y * wv, x.z * wv, x.w * wv);
        }
    } else if (level == 1) {
        int r4 = sl * 1792 + t;                       // [0, 25088)
        const float4* src = f1 + (size_t)b * 25088;
        float4* dst = out + (size_t)b * SLAB4 + 100352;
        #pragma unroll
        for (int k = 0; k < 7; ++k, r4 += 256) {
            float4 x = src[r4];
            float wv = wsm[(uint32_t)r4 / 49u];       // 49 f4 per channel
            dst[r4] = make_float4(x.x * wv, x.y * wv, x.z * wv, x.w * wv);
        }
    } else {
        int r4 = sl * 3136 + t;                       // [0, 6272)
        int end = sl * 3136 + 3136;
        const float4* src = f2 + (size_t)b * 6272;
        float4* dst = out + (size_t)b * SLAB4 + 125440;
        #pragma unroll
        for (int k = 0; k < 13; ++k, r4 += 256) {
            if (r4 < end) {
                float4 x = src[r4];
                uint32_t e = (uint32_t)r4 * 4u;       // element idx, 49 floats/channel
                float4 y = make_float4(x.x * wsm[e / 49u],
                                       x.y * wsm[(e + 1u) / 49u],
                                       x.z * wsm[(e + 2u) / 49u],
                                       x.w * wsm[(e + 3u) / 49u]);
                dst[r4] = y;
            }
        }
    }
}

// --------------------------------------------------------------------------
extern "C" void kernel_launch(void* const* d_in, const int* in_sizes, int n_in,
                              void* d_out, int out_size, void* d_ws, size_t ws_size,
                              hipStream_t stream) {
    const float* confs = (const float*)d_in[0];   // [16][32]
    const float* boxes = (const float*)d_in[1];   // [16][32][4]
    const float* f0 = (const float*)d_in[2];      // [16][512][28][28]
    const float* f1 = (const float*)d_in[3];      // [16][512][14][14]
    const float* f2 = (const float*)d_in[4];      // [16][512][7][7]
    float* out = (float*)d_out;

    float* ws = (float*)d_ws;
    float* att = ws;                               // 16*1040  = 16640 floats
    float* logits = ws + B * ATT_STRIDE;           // 3*16*512 = 24576 floats

    att_kernel<<<B, 256, 0, stream>>>(confs, boxes, att);
    logits_kernel<<<B * C / 4, 256, 0, stream>>>(f0, f1, f2, att, logits);
    scale_kernel<<<1152, 256, 0, stream>>>((const float4*)f0, (const float4*)f1,
                                           (const float4*)f2, logits, (float4*)out);
}

// Round 7
// 107.904 us; speedup vs baseline: 1.7464x; 1.5294x over previous
//
#include <hip/hip_runtime.h>
#include <hip/hip_bf16.h>
#include <stdint.h>

#define B 16
#define N 32
#define C 512
#define FEAT 224

// ------- Kernel A: conf map -> sigmoid -> avgpool8, per-pixel parallel -----
// grid = B*28 (one 8-row cell-band per block), block = 256 (4 waves).
// Each thread: 7 pixels. Output att[b][784] (28x28 pool-8 map).
__global__ __launch_bounds__(256) void att_kernel(const float* __restrict__ confs,
                                                  const float* __restrict__ boxes,
                                                  float* __restrict__ att /* [B][784] */) {
    int b = blockIdx.x / 28;
    int cy = blockIdx.x % 28;
    int t = threadIdx.x;

    __shared__ int4 ib[N];
    __shared__ float sconf[N];
    __shared__ uint32_t cm[FEAT];
    __shared__ uint32_t rm[8];
    __shared__ float spix[8 * FEAT];    // sigmoid values for the band
    __shared__ float colsum[FEAT];

    if (t < N) {
        const float* bb = boxes + (size_t)(b * N + t) * 4;
        int x1 = (int)floorf(bb[0] * 224.f);
        int y1 = (int)floorf(bb[1] * 224.f);
        int x2 = (int)floorf(bb[2] * 224.f);
        int y2 = (int)floorf(bb[3] * 224.f);
        ib[t] = make_int4(x1, y1, x2, y2);
        sconf[t] = confs[b * N + t];
    }
    __syncthreads();

    if (t < FEAT) {
        uint32_t c = 0;
        for (int n = 0; n < N; ++n) {
            int4 v = ib[n];
            if (t >= v.x && t < v.z) c |= (1u << n);
        }
        cm[t] = c;
    } else if (t < FEAT + 8) {
        int y = cy * 8 + (t - FEAT);
        uint32_t r = 0;
        for (int n = 0; n < N; ++n) {
            int4 v = ib[n];
            if (y >= v.y && y < v.w) r |= (1u << n);
        }
        rm[t - FEAT] = r;
    }
    __syncthreads();

    // 8*224 = 1792 pixels, 7 per thread
    #pragma unroll
    for (int k = 0; k < 7; ++k) {
        int p = t + k * 256;
        int yl = p / FEAT, x = p - yl * FEAT;
        uint32_t m = rm[yl] & cm[x];
        float v = 0.f;
        while (m) {
            int n = __ffs(m) - 1;
            v += sconf[n];
            m &= m - 1;
        }
        spix[p] = 1.f / (1.f + __expf(-v));   // sigmoid
    }
    __syncthreads();

    if (t < FEAT) {
        float cs = 0.f;
        #pragma unroll
        for (int yl = 0; yl < 8; ++yl) cs += spix[yl * FEAT + t];
        colsum[t] = cs;
    }
    __syncthreads();

    if (t < 28) {
        float sum = 0.f;
        #pragma unroll
        for (int dx = 0; dx < 8; ++dx) sum += colsum[t * 8 + dx];
        att[b * 784 + cy * 28 + t] = sum * (1.f / 64.f);
    }
}

// ---------------- Kernel B: logits[l][b][c] = sum_hw feat*att -------------
// grid = B * C/4 = 2048 blocks, block = 256 (4 waves), one wave per channel
__global__ __launch_bounds__(256) void logits_kernel(const float* __restrict__ f0,
                                                     const float* __restrict__ f1,
                                                     const float* __restrict__ f2,
                                                     const float* __restrict__ att,
                                                     float* __restrict__ logits /* [3][B][C] */) {
    int b = blockIdx.x >> 7;          // / 128
    int cg = blockIdx.x & 127;        // channel group of 4
    int t = threadIdx.x;

    __shared__ __align__(16) float a8[784];
    __shared__ __align__(16) float a16[196];
    __shared__ float a32[49];

    {
        const float4* abv = (const float4*)(att + b * 784);
        float4* a8v = (float4*)a8;
        if (t < 196) a8v[t] = abv[t];
    }
    __syncthreads();
    if (t < 196) {
        int i = t / 14, j = t % 14;
        a16[t] = 0.25f * (a8[(2 * i) * 28 + 2 * j] + a8[(2 * i) * 28 + 2 * j + 1] +
                          a8[(2 * i + 1) * 28 + 2 * j] + a8[(2 * i + 1) * 28 + 2 * j + 1]);
    }
    __syncthreads();
    if (t < 49) {
        int i = t / 7, j = t % 7;
        a32[t] = 0.25f * (a16[(2 * i) * 14 + 2 * j] + a16[(2 * i) * 14 + 2 * j + 1] +
                          a16[(2 * i + 1) * 14 + 2 * j] + a16[(2 * i + 1) * 14 + 2 * j + 1]);
    }
    __syncthreads();

    int wave = t >> 6, lane = t & 63;
    int c = cg * 4 + wave;

    const float4* p0 = (const float4*)(f0 + (size_t)(b * C + c) * 784); // 196 float4
    const float4* p1 = (const float4*)(f1 + (size_t)(b * C + c) * 196); // 49 float4
    const float*  p2 = f2 + (size_t)(b * C + c) * 49;                   // 49 floats
    const float4* a8v = (const float4*)a8;
    const float4* a16v = (const float4*)a16;

    float4 x0 = p0[lane];
    float4 x1 = p0[lane + 64];
    float4 x2 = p0[lane + 128];
    float4 x3 = (lane < 4) ? p0[lane + 192] : make_float4(0.f, 0.f, 0.f, 0.f);
    float4 y0 = (lane < 49) ? p1[lane] : make_float4(0.f, 0.f, 0.f, 0.f);
    float  z0 = (lane < 49) ? p2[lane] : 0.f;

    float4 b0 = a8v[lane];
    float4 b1 = a8v[lane + 64];
    float4 b2 = a8v[lane + 128];
    float4 b3 = (lane < 4) ? a8v[lane + 192] : make_float4(0.f, 0.f, 0.f, 0.f);

    float s0 = x0.x * b0.x + x0.y * b0.y + x0.z * b0.z + x0.w * b0.w;
    s0 += x1.x * b1.x + x1.y * b1.y + x1.z * b1.z + x1.w * b1.w;
    s0 += x2.x * b2.x + x2.y * b2.y + x2.z * b2.z + x2.w * b2.w;
    s0 += x3.x * b3.x + x3.y * b3.y + x3.z * b3.z + x3.w * b3.w;

    float s1 = 0.f, s2 = 0.f;
    if (lane < 49) {
        float4 c1 = a16v[lane];
        s1 = y0.x * c1.x + y0.y * c1.y + y0.z * c1.z + y0.w * c1.w;
        s2 = z0 * a32[lane];
    }

    for (int o = 32; o; o >>= 1) {
        s0 += __shfl_down(s0, o);
        s1 += __shfl_down(s1, o);
        s2 += __shfl_down(s2, o);
    }
    if (lane == 0) {
        int idx = b * C + c;
        logits[idx] = s0;
        logits[B * C + idx] = s1;
        logits[2 * B * C + idx] = s2;
    }
}

// ------- Kernel C: softmax(logits row) in-block, then out = feat * w -------
// grid = 1152: L0 = 16b x 56 slices (1792 f4), L1 = 16 x 14 (1792), L2 = 16 x 2 (3136)
#define SLAB4 131712                 // 526848/4 per-batch out float4s

__global__ __launch_bounds__(256) void scale_kernel(const float4* __restrict__ f0,
                                                    const float4* __restrict__ f1,
                                                    const float4* __restrict__ f2,
                                                    const float* __restrict__ logits /* [3][B][C] */,
                                                    float4* __restrict__ out) {
    int bid = blockIdx.x;
    int t = threadIdx.x;
    int level, b, sl;
    if (bid < 896)       { level = 0; b = bid / 56;          sl = bid % 56; }
    else if (bid < 1120) { level = 1; b = (bid - 896) / 14;  sl = (bid - 896) % 14; }
    else                 { level = 2; b = (bid - 1120) >> 1; sl = (bid - 1120) & 1; }

    // ---- block softmax over C for (level, b) ----
    __shared__ float wsm[C];
    __shared__ float red[8];
    int wave = t >> 6, lane = t & 63;
    const float* lp = logits + (level * B + b) * C;
    float v0 = lp[t], v1 = lp[t + 256];
    float mx = fmaxf(v0, v1);
    for (int o = 32; o; o >>= 1) mx = fmaxf(mx, __shfl_xor(mx, o));
    if (lane == 0) red[wave] = mx;
    __syncthreads();
    mx = fmaxf(fmaxf(red[0], red[1]), fmaxf(red[2], red[3]));
    float e0 = __expf(v0 - mx), e1 = __expf(v1 - mx);
    float s = e0 + e1;
    for (int o = 32; o; o >>= 1) s += __shfl_xor(s, o);
    if (lane == 0) red[4 + wave] = s;
    __syncthreads();
    float inv = 1.f / (red[4] + red[5] + red[6] + red[7]);
    wsm[t] = e0 * inv;
    wsm[t + 256] = e1 * inv;
    __syncthreads();

    // ---- stream the slice ----
    if (level == 0) {
        int r4 = sl * 1792 + t;                       // [0, 100352)
        const float4* src = f0 + (size_t)b * 100352;
        float4* dst = out + (size_t)b * SLAB4;
        #pragma unroll
        for (int k = 0; k < 7; ++k, r4 += 256) {
            float4 x = src[r4];
            float wv = wsm[(uint32_t)r4 / 196u];      // 196 f4 per channel
            dst[r4] = make_float4(x.x * wv, x.y * wv, x.z * wv, x.w * wv);
        }
    } else if (level == 1) {
        int r4 = sl * 1792 + t;                       // [0, 25088)
        const float4* src = f1 + (size_t)b * 25088;
        float4* dst = out + (size_t)b * SLAB4 + 100352;
        #pragma unroll
        for (int k = 0; k < 7; ++k, r4 += 256) {
            float4 x = src[r4];
            float wv = wsm[(uint32_t)r4 / 49u];       // 49 f4 per channel
            dst[r4] = make_float4(x.x * wv, x.y * wv, x.z * wv, x.w * wv);
        }
    } else {
        int r4 = sl * 3136 + t;                       // [0, 6272)
        int end = sl * 3136 + 3136;
        const float4* src = f2 + (size_t)b * 6272;
        float4* dst = out + (size_t)b * SLAB4 + 125440;
        #pragma unroll
        for (int k = 0; k < 13; ++k, r4 += 256) {
            if (r4 < end) {
                float4 x = src[r4];
                uint32_t e = (uint32_t)r4 * 4u;       // element idx, 49 floats/channel
                float4 y = make_float4(x.x * wsm[e / 49u],
                                       x.y * wsm[(e + 1u) / 49u],
                                       x.z * wsm[(e + 2u) / 49u],
                                       x.w * wsm[(e + 3u) / 49u]);
                dst[r4] = y;
            }
        }
    }
}

// --------------------------------------------------------------------------
extern "C" void kernel_launch(void* const* d_in, const int* in_sizes, int n_in,
                              void* d_out, int out_size, void* d_ws, size_t ws_size,
                              hipStream_t stream) {
    const float* confs = (const float*)d_in[0];   // [16][32]
    const float* boxes = (const float*)d_in[1];   // [16][32][4]
    const float* f0 = (const float*)d_in[2];      // [16][512][28][28]
    const float* f1 = (const float*)d_in[3];      // [16][512][14][14]
    const float* f2 = (const float*)d_in[4];      // [16][512][7][7]
    float* out = (float*)d_out;

    float* ws = (float*)d_ws;
    float* att = ws;                       // 16*784  = 12544 floats
    float* logits = ws + 12544;            // 3*16*512 = 24576 floats

    att_kernel<<<B * 28, 256, 0, stream>>>(confs, boxes, att);
    logits_kernel<<<B * C / 4, 256, 0, stream>>>(f0, f1, f2, att, logits);
    scale_kernel<<<1152, 256, 0, stream>>>((const float4*)f0, (const float4*)f1,
                                           (const float4*)f2, logits, (float4*)out);
}

// Round 8
// 107.034 us; speedup vs baseline: 1.7606x; 1.0081x over previous
//
#include <hip/hip_runtime.h>
#include <hip/hip_bf16.h>
#include <stdint.h>

#define B 16
#define N 32
#define C 512
#define FEAT 224

// ------- Kernel A: conf map -> sigmoid -> avgpool8, per-pixel parallel -----
// grid = B*28 (one 8-row cell-band per block), block = 256 (4 waves).
__global__ __launch_bounds__(256) void att_kernel(const float* __restrict__ confs,
                                                  const float* __restrict__ boxes,
                                                  float* __restrict__ att /* [B][784] */) {
    int b = blockIdx.x / 28;
    int cy = blockIdx.x % 28;
    int t = threadIdx.x;

    __shared__ int4 ib[N];
    __shared__ float sconf[N];
    __shared__ uint32_t cm[FEAT];
    __shared__ uint32_t rm[8];
    __shared__ float spix[8 * FEAT];
    __shared__ float colsum[FEAT];

    if (t < N) {
        const float* bb = boxes + (size_t)(b * N + t) * 4;
        int x1 = (int)floorf(bb[0] * 224.f);
        int y1 = (int)floorf(bb[1] * 224.f);
        int x2 = (int)floorf(bb[2] * 224.f);
        int y2 = (int)floorf(bb[3] * 224.f);
        ib[t] = make_int4(x1, y1, x2, y2);
        sconf[t] = confs[b * N + t];
    }
    __syncthreads();

    if (t < FEAT) {
        uint32_t c = 0;
        for (int n = 0; n < N; ++n) {
            int4 v = ib[n];
            if (t >= v.x && t < v.z) c |= (1u << n);
        }
        cm[t] = c;
    } else if (t < FEAT + 8) {
        int y = cy * 8 + (t - FEAT);
        uint32_t r = 0;
        for (int n = 0; n < N; ++n) {
            int4 v = ib[n];
            if (y >= v.y && y < v.w) r |= (1u << n);
        }
        rm[t - FEAT] = r;
    }
    __syncthreads();

    #pragma unroll
    for (int k = 0; k < 7; ++k) {
        int p = t + k * 256;
        int yl = p / FEAT, x = p - yl * FEAT;
        uint32_t m = rm[yl] & cm[x];
        float v = 0.f;
        while (m) {
            int n = __ffs(m) - 1;
            v += sconf[n];
            m &= m - 1;
        }
        spix[p] = 1.f / (1.f + __expf(-v));   // sigmoid
    }
    __syncthreads();

    if (t < FEAT) {
        float cs = 0.f;
        #pragma unroll
        for (int yl = 0; yl < 8; ++yl) cs += spix[yl * FEAT + t];
        colsum[t] = cs;
    }
    __syncthreads();

    if (t < 28) {
        float sum = 0.f;
        #pragma unroll
        for (int dx = 0; dx < 8; ++dx) sum += colsum[t * 8 + dx];
        att[b * 784 + cy * 28 + t] = sum * (1.f / 64.f);
    }
}

// ---------------- Kernel B: logits[l][b][c] = sum_hw feat*att -------------
// grid = B * C/8 = 1024 blocks, block = 256 (4 waves), TWO channels per wave.
__global__ __launch_bounds__(256) void logits_kernel(const float* __restrict__ f0,
                                                     const float* __restrict__ f1,
                                                     const float* __restrict__ f2,
                                                     const float* __restrict__ att,
                                                     float* __restrict__ logits /* [3][B][C] */) {
    int b = blockIdx.x >> 6;          // / 64
    int cg = blockIdx.x & 63;         // channel group of 8
    int t = threadIdx.x;

    __shared__ __align__(16) float a8[784];
    __shared__ __align__(16) float a16[196];
    __shared__ float a32[49];

    {
        const float4* abv = (const float4*)(att + b * 784);
        float4* a8v = (float4*)a8;
        if (t < 196) a8v[t] = abv[t];
    }
    __syncthreads();
    if (t < 196) {
        int i = t / 14, j = t % 14;
        a16[t] = 0.25f * (a8[(2 * i) * 28 + 2 * j] + a8[(2 * i) * 28 + 2 * j + 1] +
                          a8[(2 * i + 1) * 28 + 2 * j] + a8[(2 * i + 1) * 28 + 2 * j + 1]);
    }
    __syncthreads();
    if (t < 49) {
        int i = t / 7, j = t % 7;
        a32[t] = 0.25f * (a16[(2 * i) * 14 + 2 * j] + a16[(2 * i) * 14 + 2 * j + 1] +
                          a16[(2 * i + 1) * 14 + 2 * j] + a16[(2 * i + 1) * 14 + 2 * j + 1]);
    }
    __syncthreads();

    int wave = t >> 6, lane = t & 63;
    int cA = cg * 8 + wave * 2;       // this wave's two channels
    int cB = cA + 1;

    const float4* pA0 = (const float4*)(f0 + (size_t)(b * C + cA) * 784);
    const float4* pB0 = (const float4*)(f0 + (size_t)(b * C + cB) * 784);
    const float4* pA1 = (const float4*)(f1 + (size_t)(b * C + cA) * 196);
    const float4* pB1 = (const float4*)(f1 + (size_t)(b * C + cB) * 196);
    const float*  pA2 = f2 + (size_t)(b * C + cA) * 49;
    const float*  pB2 = f2 + (size_t)(b * C + cB) * 49;
    const float4* a8v = (const float4*)a8;
    const float4* a16v = (const float4*)a16;

    float4 z4 = make_float4(0.f, 0.f, 0.f, 0.f);
    // issue all global loads up front (12 per wave)
    float4 xA0 = pA0[lane];
    float4 xA1 = pA0[lane + 64];
    float4 xA2 = pA0[lane + 128];
    float4 xA3 = (lane < 4) ? pA0[lane + 192] : z4;
    float4 xB0 = pB0[lane];
    float4 xB1 = pB0[lane + 64];
    float4 xB2 = pB0[lane + 128];
    float4 xB3 = (lane < 4) ? pB0[lane + 192] : z4;
    float4 yA = (lane < 49) ? pA1[lane] : z4;
    float4 yB = (lane < 49) ? pB1[lane] : z4;
    float  zA = (lane < 49) ? pA2[lane] : 0.f;
    float  zB = (lane < 49) ? pB2[lane] : 0.f;

    // att fragments from LDS, shared by both channels
    float4 b0 = a8v[lane];
    float4 b1 = a8v[lane + 64];
    float4 b2 = a8v[lane + 128];
    float4 b3 = (lane < 4) ? a8v[lane + 192] : z4;

    float sA0 = xA0.x * b0.x + xA0.y * b0.y + xA0.z * b0.z + xA0.w * b0.w;
    sA0 += xA1.x * b1.x + xA1.y * b1.y + xA1.z * b1.z + xA1.w * b1.w;
    sA0 += xA2.x * b2.x + xA2.y * b2.y + xA2.z * b2.z + xA2.w * b2.w;
    sA0 += xA3.x * b3.x + xA3.y * b3.y + xA3.z * b3.z + xA3.w * b3.w;
    float sB0 = xB0.x * b0.x + xB0.y * b0.y + xB0.z * b0.z + xB0.w * b0.w;
    sB0 += xB1.x * b1.x + xB1.y * b1.y + xB1.z * b1.z + xB1.w * b1.w;
    sB0 += xB2.x * b2.x + xB2.y * b2.y + xB2.z * b2.z + xB2.w * b2.w;
    sB0 += xB3.x * b3.x + xB3.y * b3.y + xB3.z * b3.z + xB3.w * b3.w;

    float sA1 = 0.f, sA2 = 0.f, sB1 = 0.f, sB2 = 0.f;
    if (lane < 49) {
        float4 c1 = a16v[lane];
        float a32l = a32[lane];
        sA1 = yA.x * c1.x + yA.y * c1.y + yA.z * c1.z + yA.w * c1.w;
        sB1 = yB.x * c1.x + yB.y * c1.y + yB.z * c1.z + yB.w * c1.w;
        sA2 = zA * a32l;
        sB2 = zB * a32l;
    }

    for (int o = 32; o; o >>= 1) {
        sA0 += __shfl_down(sA0, o);
        sA1 += __shfl_down(sA1, o);
        sA2 += __shfl_down(sA2, o);
        sB0 += __shfl_down(sB0, o);
        sB1 += __shfl_down(sB1, o);
        sB2 += __shfl_down(sB2, o);
    }
    if (lane == 0) {
        int idxA = b * C + cA;
        logits[idxA] = sA0;
        logits[B * C + idxA] = sA1;
        logits[2 * B * C + idxA] = sA2;
        logits[idxA + 1] = sB0;
        logits[B * C + idxA + 1] = sB1;
        logits[2 * B * C + idxA + 1] = sB2;
    }
}

// ------- Kernel C: softmax(logits row) in-block, then out = feat * w -------
// grid = 2080: L0 = 16b x 98 slices (1024 f4 exact), L1 = 16 x 25 (<=1024),
//              L2 = 16 x 7 (896 f4 exact)
#define SLAB4 131712                 // 526848/4 per-batch out float4s

__global__ __launch_bounds__(256) void scale_kernel(const float4* __restrict__ f0,
                                                    const float4* __restrict__ f1,
                                                    const float4* __restrict__ f2,
                                                    const float* __restrict__ logits /* [3][B][C] */,
                                                    float4* __restrict__ out) {
    int bid = blockIdx.x;
    int t = threadIdx.x;
    int level, b, sl;
    if (bid < 1568)      { level = 0; b = bid / 98;          sl = bid % 98; }
    else if (bid < 1968) { level = 1; b = (bid - 1568) / 25; sl = (bid - 1568) % 25; }
    else                 { level = 2; b = (bid - 1968) / 7;  sl = (bid - 1968) % 7; }

    // ---- block softmax over C for (level, b) ----
    __shared__ float wsm[C];
    __shared__ float red[8];
    int wave = t >> 6, lane = t & 63;
    const float* lp = logits + (level * B + b) * C;
    float v0 = lp[t], v1 = lp[t + 256];
    float mx = fmaxf(v0, v1);
    for (int o = 32; o; o >>= 1) mx = fmaxf(mx, __shfl_xor(mx, o));
    if (lane == 0) red[wave] = mx;
    __syncthreads();
    mx = fmaxf(fmaxf(red[0], red[1]), fmaxf(red[2], red[3]));
    float e0 = __expf(v0 - mx), e1 = __expf(v1 - mx);
    float s = e0 + e1;
    for (int o = 32; o; o >>= 1) s += __shfl_xor(s, o);
    if (lane == 0) red[4 + wave] = s;
    __syncthreads();
    float inv = 1.f / (red[4] + red[5] + red[6] + red[7]);
    wsm[t] = e0 * inv;
    wsm[t + 256] = e1 * inv;
    __syncthreads();

    // ---- stream the slice ----
    if (level == 0) {
        int r4 = sl * 1024 + t;                       // [0, 100352), exact
        const float4* src = f0 + (size_t)b * 100352;
        float4* dst = out + (size_t)b * SLAB4;
        #pragma unroll
        for (int k = 0; k < 4; ++k, r4 += 256) {
            float4 x = src[r4];
            float wv = wsm[(uint32_t)r4 / 196u];      // 196 f4 per channel
            dst[r4] = make_float4(x.x * wv, x.y * wv, x.z * wv, x.w * wv);
        }
    } else if (level == 1) {
        int r4 = sl * 1024 + t;                       // [0, 25088), last slice short
        const float4* src = f1 + (size_t)b * 25088;
        float4* dst = out + (size_t)b * SLAB4 + 100352;
        #pragma unroll
        for (int k = 0; k < 4; ++k, r4 += 256) {
            if (r4 < 25088) {
                float4 x = src[r4];
                float wv = wsm[(uint32_t)r4 / 49u];   // 49 f4 per channel
                dst[r4] = make_float4(x.x * wv, x.y * wv, x.z * wv, x.w * wv);
            }
        }
    } else {
        const float4* src = f2 + (size_t)b * 6272;
        float4* dst = out + (size_t)b * SLAB4 + 125440;
        #pragma unroll
        for (int k = 0; k < 4; ++k) {
            int idx = t + k * 256;
            if (idx < 896) {
                int r4 = sl * 896 + idx;              // [0, 6272), exact
                float4 x = src[r4];
                uint32_t e = (uint32_t)r4 * 4u;       // element idx, 49 floats/channel
                float4 y = make_float4(x.x * wsm[e / 49u],
                                       x.y * wsm[(e + 1u) / 49u],
                                       x.z * wsm[(e + 2u) / 49u],
                                       x.w * wsm[(e + 3u) / 49u]);
                dst[r4] = y;
            }
        }
    }
}

// --------------------------------------------------------------------------
extern "C" void kernel_launch(void* const* d_in, const int* in_sizes, int n_in,
                              void* d_out, int out_size, void* d_ws, size_t ws_size,
                              hipStream_t stream) {
    const float* confs = (const float*)d_in[0];   // [16][32]
    const float* boxes = (const float*)d_in[1];   // [16][32][4]
    const float* f0 = (const float*)d_in[2];      // [16][512][28][28]
    const float* f1 = (const float*)d_in[3];      // [16][512][14][14]
    const float* f2 = (const float*)d_in[4];      // [16][512][7][7]
    float* out = (float*)d_out;

    float* ws = (float*)d_ws;
    float* att = ws;                       // 16*784  = 12544 floats
    float* logits = ws + 12544;            // 3*16*512 = 24576 floats

    att_kernel<<<B * 28, 256, 0, stream>>>(confs, boxes, att);
    logits_kernel<<<B * C / 8, 256, 0, stream>>>(f0, f1, f2, att, logits);
    scale_kernel<<<2080, 256, 0, stream>>>((const float4*)f0, (const float4*)f1,
                                           (const float4*)f2, logits, (float4*)out);
}